// Round 5
// baseline (63.189 us; speedup 1.0000x reference)
//
#include <hip/hip_runtime.h>
#include <hip/hip_fp16.h>

// GCN layer: out[N,16] = segment_sum(vals[e] * embeds[col[e], :], row[e])
// Round 5: rounds 3/4 proved the limiter is gather latency/issue, not BW
// (157MB and 54MB fetch -> same 46-50us). Fix: explicit 3-deep software
// pipeline, 8 edges/iter -> ~12 loads in flight per wave, branch-free body
// (prefetch addresses clamped, stray edges masked by weight=0).

#define D 16
constexpr int BLOCK = 256;

typedef float f32x4 __attribute__((ext_vector_type(4)));
typedef int   i32x4 __attribute__((ext_vector_type(4)));
typedef unsigned int u32x2 __attribute__((ext_vector_type(2)));
typedef unsigned int u32x4 __attribute__((ext_vector_type(4)));

struct M8 { i32x4 ca, cb; f32x4 va, vb; };                 // 8 edges' metadata
struct G8 { u32x2 g0, g1, g2, g3, g4, g5, g6, g7; };       // 8 gathered rows

__device__ inline float2 h2f(unsigned int u) {
  union { unsigned int u; __half2 h; } cv;
  cv.u = u;
  return __half22float2(cv.h);
}

__device__ inline M8 load_meta8(const int* __restrict__ col,
                                const float* __restrict__ vals, int e) {
  M8 m;
  m.ca = __builtin_nontemporal_load((const i32x4*)(col + e));
  m.cb = __builtin_nontemporal_load((const i32x4*)(col + e + 4));
  m.va = __builtin_nontemporal_load((const f32x4*)(vals + e));
  m.vb = __builtin_nontemporal_load((const f32x4*)(vals + e + 4));
  return m;
}

__device__ inline G8 gather8(const __half* __restrict__ tbl, const M8& m, int q4) {
  G8 g;
  g.g0 = *(const u32x2*)(tbl + (m.ca[0] << 4) + q4);
  g.g1 = *(const u32x2*)(tbl + (m.ca[1] << 4) + q4);
  g.g2 = *(const u32x2*)(tbl + (m.ca[2] << 4) + q4);
  g.g3 = *(const u32x2*)(tbl + (m.ca[3] << 4) + q4);
  g.g4 = *(const u32x2*)(tbl + (m.cb[0] << 4) + q4);
  g.g5 = *(const u32x2*)(tbl + (m.cb[1] << 4) + q4);
  g.g6 = *(const u32x2*)(tbl + (m.cb[2] << 4) + q4);
  g.g7 = *(const u32x2*)(tbl + (m.cb[3] << 4) + q4);
  return g;
}

__device__ inline void consume8(f32x4& acc, const M8& m, const G8& g,
                                int e, int beg, int end) {
#define EDGE(i, gg, vv)                                          \
  {                                                              \
    float w = (e + i >= beg && e + i < end) ? (vv) : 0.f;        \
    float2 lo = h2f(gg[0]), hi = h2f(gg[1]);                     \
    acc[0] = fmaf(w, lo.x, acc[0]);                              \
    acc[1] = fmaf(w, lo.y, acc[1]);                              \
    acc[2] = fmaf(w, hi.x, acc[2]);                              \
    acc[3] = fmaf(w, hi.y, acc[3]);                              \
  }
  EDGE(0, g.g0, m.va[0])
  EDGE(1, g.g1, m.va[1])
  EDGE(2, g.g2, m.va[2])
  EDGE(3, g.g3, m.va[3])
  EDGE(4, g.g4, m.vb[0])
  EDGE(5, g.g5, m.vb[1])
  EDGE(6, g.g6, m.vb[2])
  EDGE(7, g.g7, m.vb[3])
#undef EDGE
}

// Fused prep: repack embeds f32->f16 (task A) + row_ptr adjacent-diff (task B).
__global__ __launch_bounds__(BLOCK) void prep_kernel(
    const int* __restrict__ row, int E,
    const float* __restrict__ embeds, int N,
    int* __restrict__ row_ptr, __half* __restrict__ table) {
  const long long t = (long long)blockIdx.x * BLOCK + threadIdx.x;

  if (table != nullptr) {
    const long long nchunkA = (long long)N * 2;  // 8 halves per chunk
    if (t < nchunkA) {
      const f32x4* src = (const f32x4*)embeds + t * 2;
      f32x4 a = __builtin_nontemporal_load(src);
      f32x4 b = __builtin_nontemporal_load(src + 1);
      union { __half2 h[4]; u32x4 u; } o;
      o.h[0] = __floats2half2_rn(a[0], a[1]);
      o.h[1] = __floats2half2_rn(a[2], a[3]);
      o.h[2] = __floats2half2_rn(b[0], b[1]);
      o.h[3] = __floats2half2_rn(b[2], b[3]);
      *((u32x4*)table + t) = o.u;  // cached store: we WANT this in L2
    }
  }

  const long long e = t * 4;
  if (e < E) {
    int prev = (e == 0) ? -1 : row[e - 1];
    const int cnt = (E - e >= 4) ? 4 : (int)(E - e);
    int r[4];
    if (cnt == 4) {
      i32x4 r4 = __builtin_nontemporal_load((const i32x4*)(row + e));
      r[0] = r4[0]; r[1] = r4[1]; r[2] = r4[2]; r[3] = r4[3];
    } else {
      for (int k = 0; k < cnt; ++k) r[k] = row[e + k];
    }
    for (int k = 0; k < cnt; ++k) {
      for (int n = prev + 1; n <= r[k]; ++n) row_ptr[n] = (int)e + k;
      prev = r[k];
    }
    if (e + cnt == E) {
      for (int n = prev + 1; n <= N; ++n) row_ptr[n] = E;
    }
  }
}

// K2: 4 lanes/node, lane q owns features [4q..4q+3]; 3-deep pipeline.
__global__ __launch_bounds__(BLOCK) void gcn_node_half_kernel(
    const int* __restrict__ col, const float* __restrict__ vals,
    const __half* __restrict__ table, const int* __restrict__ row_ptr,
    f32x4* __restrict__ out4, int N, int E) {
  const int t = blockIdx.x * BLOCK + threadIdx.x;
  const int node = t >> 2;
  const int q = t & 3;
  if (node >= N) return;

  const int beg = row_ptr[node];
  const int end = row_ptr[node + 1];
  const int q4 = q << 2;

  const int Ea = E & ~7;        // aligned region handled by the pipeline
  const int eMax = Ea - 8;      // last valid 8-chunk start (E >= 8 always here)

  int e0 = beg & ~7;          if (e0 > eMax) e0 = eMax;
  int e1 = (end + 7) & ~7;    if (e1 > Ea) e1 = Ea;
  int nch = (e1 - e0) >> 3;   if (nch < 1) nch = 1;  // empty nodes: 1 masked chunk

  f32x4 acc = {0.f, 0.f, 0.f, 0.f};

  int e = e0;
  int ep1 = e + 8;  if (ep1 > eMax) ep1 = eMax;
  M8 m0 = load_meta8(col, vals, e);
  M8 m1 = load_meta8(col, vals, ep1);
  G8 g0 = gather8(table, m0, q4);

  for (int k = 0; k < nch; ++k) {
    int ep2 = e + 16;  if (ep2 > eMax) ep2 = eMax;
    M8 m2 = load_meta8(col, vals, ep2);   // prefetch metadata (k+2)
    G8 g1 = gather8(table, m1, q4);       // prefetch gathers  (k+1)
    consume8(acc, m0, g0, e, beg, end);   // consume           (k)
    m0 = m1; m1 = m2; g0 = g1;
    e += 8;
  }

  // Scalar tail (only if E % 8 != 0 and this node's range crosses Ea).
  for (int te = (Ea > beg ? Ea : beg); te < end; ++te) {
    float v = vals[te];
    u32x2 gg = *(const u32x2*)(table + (col[te] << 4) + q4);
    float2 lo = h2f(gg[0]), hi = h2f(gg[1]);
    acc[0] = fmaf(v, lo.x, acc[0]);
    acc[1] = fmaf(v, lo.y, acc[1]);
    acc[2] = fmaf(v, hi.x, acc[2]);
    acc[3] = fmaf(v, hi.y, acc[3]);
  }

  __builtin_nontemporal_store(acc, out4 + (long long)node * 4 + q);
}

// Fallback K2 (f32 gathers straight from embeds) if ws can't hold the table.
__global__ __launch_bounds__(BLOCK) void gcn_node_f32_kernel(
    const int* __restrict__ col, const float* __restrict__ vals,
    const f32x4* __restrict__ embeds4, const int* __restrict__ row_ptr,
    f32x4* __restrict__ out4, int N, int E) {
  const int t = blockIdx.x * BLOCK + threadIdx.x;
  const int node = t >> 2;
  const int q = t & 3;
  if (node >= N) return;
  const int beg = row_ptr[node];
  const int end = row_ptr[node + 1];
  f32x4 acc = {0.f, 0.f, 0.f, 0.f};
  int e0 = beg & ~3;
  int e1 = (end + 3) & ~3;
  if (e1 > E) e1 = E & ~3;
  #pragma unroll 2
  for (int e = e0; e < e1; e += 4) {
    i32x4 c4 = __builtin_nontemporal_load((const i32x4*)(col + e));
    f32x4 v4 = __builtin_nontemporal_load((const f32x4*)(vals + e));
    float w0 = (e + 0 >= beg && e + 0 < end) ? v4[0] : 0.f;
    float w1 = (e + 1 >= beg && e + 1 < end) ? v4[1] : 0.f;
    float w2 = (e + 2 >= beg && e + 2 < end) ? v4[2] : 0.f;
    float w3 = (e + 3 >= beg && e + 3 < end) ? v4[3] : 0.f;
    f32x4 x0 = embeds4[(long long)c4[0] * 4 + q];
    f32x4 x1 = embeds4[(long long)c4[1] * 4 + q];
    f32x4 x2 = embeds4[(long long)c4[2] * 4 + q];
    f32x4 x3 = embeds4[(long long)c4[3] * 4 + q];
    acc += w0 * x0 + w1 * x1;
    acc += w2 * x2 + w3 * x3;
  }
  for (int e = (e1 > beg ? e1 : beg); e < end; ++e) {
    acc += vals[e] * embeds4[(long long)col[e] * 4 + q];
  }
  __builtin_nontemporal_store(acc, out4 + (long long)node * 4 + q);
}

extern "C" void kernel_launch(void* const* d_in, const int* in_sizes, int n_in,
                              void* d_out, int out_size, void* d_ws, size_t ws_size,
                              hipStream_t stream) {
  const int*   row    = (const int*)d_in[0];
  const int*   col    = (const int*)d_in[1];
  const float* vals   = (const float*)d_in[2];
  const float* embeds = (const float*)d_in[3];

  const int E = in_sizes[0];
  const int N = in_sizes[3] / D;

  const size_t rp_bytes = ((size_t)(N + 1) * 4 + 511) & ~(size_t)511;
  const size_t tbl_bytes = (size_t)N * D * sizeof(__half);
  const bool use_half = (ws_size >= rp_bytes + tbl_bytes) && (E >= 8);

  int*    row_ptr = (int*)d_ws;
  __half* table   = use_half ? (__half*)((char*)d_ws + rp_bytes) : nullptr;

  {
    long long chunksB = ((long long)E + 3) / 4;
    long long chunksA = use_half ? (long long)N * 2 : 0;
    long long threads = chunksB > chunksA ? chunksB : chunksA;
    int grid = (int)((threads + BLOCK - 1) / BLOCK);
    prep_kernel<<<grid, BLOCK, 0, stream>>>(row, E, embeds, N, row_ptr, table);
  }
  {
    long long threads = (long long)N * 4;
    int grid = (int)((threads + BLOCK - 1) / BLOCK);
    if (use_half) {
      gcn_node_half_kernel<<<grid, BLOCK, 0, stream>>>(
          col, vals, table, row_ptr, (f32x4*)d_out, N, E);
    } else {
      gcn_node_f32_kernel<<<grid, BLOCK, 0, stream>>>(
          col, vals, (const f32x4*)embeds, row_ptr, (f32x4*)d_out, N, E);
    }
  }
}

// Round 6
// 38.419 us; speedup vs baseline: 1.6448x; 1.6448x over previous
//
#include <hip/hip_runtime.h>
#include <hip/hip_fp16.h>

// GCN layer: out[N,16] = segment_sum(vals[e] * embeds[col[e], :], row[e])
// Round 6: round-5's reg pipeline collapsed (VGPR stayed 36) because gather
// addresses depended on global metadata loads -> shared vmcnt forced drains.
// Fix: stage metadata in LDS (block-cooperative, coalesced). Gather addresses
// now come via lgkmcnt (ds_read); the hot loop's vmcnt holds ONLY the 8
// independent table gathers per batch -> compiler emits counted vmcnt(4)/(0)
// and latency overlaps. fp16 table (L2-resident) kept from round 4.

#define D 16
constexpr int BLOCK = 256;
constexpr int NPB = BLOCK / 4;    // 64 nodes per block (4 lanes/node)
constexpr int SMEM_E = 3072;      // staged edges per stage (24KB LDS), mult of 8

typedef float f32x4 __attribute__((ext_vector_type(4)));
typedef int   i32x4 __attribute__((ext_vector_type(4)));
typedef unsigned int u32x2 __attribute__((ext_vector_type(2)));
typedef unsigned int u32x4 __attribute__((ext_vector_type(4)));

__device__ inline float2 h2f(unsigned int u) {
  union { unsigned int u; __half2 h; } cv;
  cv.u = u;
  return __half22float2(cv.h);
}

// Fused prep: repack embeds f32->f16 (task A) + row_ptr adjacent-diff (task B).
__global__ __launch_bounds__(BLOCK) void prep_kernel(
    const int* __restrict__ row, int E,
    const float* __restrict__ embeds, int N,
    int* __restrict__ row_ptr, __half* __restrict__ table) {
  const long long t = (long long)blockIdx.x * BLOCK + threadIdx.x;

  if (table != nullptr) {
    const long long nchunkA = (long long)N * 2;  // 8 halves per chunk
    if (t < nchunkA) {
      const f32x4* src = (const f32x4*)embeds + t * 2;
      f32x4 a = __builtin_nontemporal_load(src);
      f32x4 b = __builtin_nontemporal_load(src + 1);
      union { __half2 h[4]; u32x4 u; } o;
      o.h[0] = __floats2half2_rn(a[0], a[1]);
      o.h[1] = __floats2half2_rn(a[2], a[3]);
      o.h[2] = __floats2half2_rn(b[0], b[1]);
      o.h[3] = __floats2half2_rn(b[2], b[3]);
      *((u32x4*)table + t) = o.u;  // cached store: we WANT this in L2
    }
  }

  const long long e = t * 4;
  if (e < E) {
    int prev = (e == 0) ? -1 : row[e - 1];
    const int cnt = (E - e >= 4) ? 4 : (int)(E - e);
    int r[4];
    if (cnt == 4) {
      i32x4 r4 = *(const i32x4*)(row + e);
      r[0] = r4[0]; r[1] = r4[1]; r[2] = r4[2]; r[3] = r4[3];
    } else {
      for (int k = 0; k < cnt; ++k) r[k] = row[e + k];
    }
    for (int k = 0; k < cnt; ++k) {
      for (int n = prev + 1; n <= r[k]; ++n) row_ptr[n] = (int)e + k;
      prev = r[k];
    }
    if (e + cnt == E) {
      for (int n = prev + 1; n <= N; ++n) row_ptr[n] = E;
    }
  }
}

// K2: block stages its nodes' edge window (col,val interleaved) into LDS,
// then 4-lane groups gather fp16 rows in 8-edge batches.
__global__ __launch_bounds__(BLOCK) void gcn_gather_kernel(
    const int* __restrict__ col, const float* __restrict__ vals,
    const __half* __restrict__ table, const int* __restrict__ row_ptr,
    f32x4* __restrict__ out4, int N, int E) {
  __shared__ __align__(16) unsigned int s_meta[SMEM_E * 2];  // {col,valbits}

  const int t = threadIdx.x;
  const int n0 = blockIdx.x * NPB;
  const int nEnd = (n0 + NPB < N) ? n0 + NPB : N;
  const int g = t >> 2;
  const int q = t & 3;
  const int node = n0 + g;
  const bool active = (node < nEnd);

  const int Wb = row_ptr[n0] & ~3;   // 4-aligned window base
  const int We = row_ptr[nEnd];

  const int beg = active ? row_ptr[node] : 0;
  const int end = active ? row_ptr[node + 1] : 0;
  const unsigned q8 = (unsigned)(q << 3);  // byte offset of this lane's 8B
  const char* tbl = (const char*)table;

  f32x4 acc = {0.f, 0.f, 0.f, 0.f};

  for (int W0 = Wb; W0 < We; W0 += SMEM_E) {
    const int cnt  = (SMEM_E < We - W0) ? SMEM_E : (We - W0);
    const int cntP = (cnt + 7) & ~7;   // <= SMEM_E (SMEM_E mult of 8)
    __syncthreads();  // protect s_meta reuse across stages
    // Cooperative coalesced staging: 4 edges per thread per iteration.
    for (int i = t * 4; i < cntP; i += BLOCK * 4) {
      const int e = W0 + i;
      u32x4 lo, hi;
      if (e + 3 < E) {
        i32x4 c4 = *(const i32x4*)(col + e);
        f32x4 v4 = *(const f32x4*)(vals + e);
        lo = (u32x4){(unsigned)c4[0], __float_as_uint(v4[0]),
                     (unsigned)c4[1], __float_as_uint(v4[1])};
        hi = (u32x4){(unsigned)c4[2], __float_as_uint(v4[2]),
                     (unsigned)c4[3], __float_as_uint(v4[3])};
      } else {
        unsigned cc[4], vv[4];
        for (int k = 0; k < 4; ++k) {
          cc[k] = (e + k < E) ? (unsigned)col[e + k] : 0u;
          vv[k] = (e + k < E) ? __float_as_uint(vals[e + k]) : 0u;
        }
        lo = (u32x4){cc[0], vv[0], cc[1], vv[1]};
        hi = (u32x4){cc[2], vv[2], cc[3], vv[3]};
      }
      *(u32x4*)(s_meta + (size_t)i * 2)     = lo;
      *(u32x4*)(s_meta + (size_t)i * 2 + 4) = hi;
    }
    __syncthreads();

    const int gb = (beg > W0) ? beg : W0;
    const int ge = (end < W0 + cnt) ? end : (W0 + cnt);
    if (ge > gb) {
      const unsigned span = (unsigned)(ge - gb);
      const int e0 = W0 + ((gb - W0) & ~7);               // 8-aligned in window
      const int e1 = e0 + ((ge - e0 + 7) & ~7);           // <= W0 + cntP
      for (int e = e0; e < e1; e += 8) {
        const int idx = (e - W0) * 2;
        // Metadata via LDS (lgkmcnt) -- same-address 4-lane reads broadcast.
        u32x4 mA = *(const u32x4*)(s_meta + idx);       // c0 v0 c1 v1
        u32x4 mB = *(const u32x4*)(s_meta + idx + 4);   // c2 v2 c3 v3
        u32x4 mC = *(const u32x4*)(s_meta + idx + 8);   // c4 v4 c5 v5
        u32x4 mD = *(const u32x4*)(s_meta + idx + 12);  // c6 v6 c7 v7
        // 8 independent 8B gathers -> only vmcnt traffic in the loop.
        u32x2 g0 = *(const u32x2*)(tbl + (size_t)((mA[0] << 5) + q8));
        u32x2 g1 = *(const u32x2*)(tbl + (size_t)((mA[2] << 5) + q8));
        u32x2 g2 = *(const u32x2*)(tbl + (size_t)((mB[0] << 5) + q8));
        u32x2 g3 = *(const u32x2*)(tbl + (size_t)((mB[2] << 5) + q8));
        u32x2 g4 = *(const u32x2*)(tbl + (size_t)((mC[0] << 5) + q8));
        u32x2 g5 = *(const u32x2*)(tbl + (size_t)((mC[2] << 5) + q8));
        u32x2 g6 = *(const u32x2*)(tbl + (size_t)((mD[0] << 5) + q8));
        u32x2 g7 = *(const u32x2*)(tbl + (size_t)((mD[2] << 5) + q8));
#define EDGE(i, gg, vbits)                                            \
        {                                                             \
          float w = ((unsigned)(e + i - gb) < span)                   \
                        ? __uint_as_float(vbits) : 0.f;               \
          float2 lo2 = h2f(gg[0]), hi2 = h2f(gg[1]);                  \
          acc[0] = fmaf(w, lo2.x, acc[0]);                            \
          acc[1] = fmaf(w, lo2.y, acc[1]);                            \
          acc[2] = fmaf(w, hi2.x, acc[2]);                            \
          acc[3] = fmaf(w, hi2.y, acc[3]);                            \
        }
        EDGE(0, g0, mA[1])
        EDGE(1, g1, mA[3])
        EDGE(2, g2, mB[1])
        EDGE(3, g3, mB[3])
        EDGE(4, g4, mC[1])
        EDGE(5, g5, mC[3])
        EDGE(6, g6, mD[1])
        EDGE(7, g7, mD[3])
#undef EDGE
      }
    }
  }

  if (active) {
    __builtin_nontemporal_store(acc, out4 + (size_t)node * 4 + q);
  }
}

// Fallback (f32 gathers straight from embeds) if ws can't hold the table.
__global__ __launch_bounds__(BLOCK) void gcn_node_f32_kernel(
    const int* __restrict__ col, const float* __restrict__ vals,
    const f32x4* __restrict__ embeds4, const int* __restrict__ row_ptr,
    f32x4* __restrict__ out4, int N, int E) {
  const int t = blockIdx.x * BLOCK + threadIdx.x;
  const int node = t >> 2;
  const int q = t & 3;
  if (node >= N) return;
  const int beg = row_ptr[node];
  const int end = row_ptr[node + 1];
  f32x4 acc = {0.f, 0.f, 0.f, 0.f};
  for (int e = beg; e < end; ++e) {
    acc += vals[e] * embeds4[(long long)col[e] * 4 + q];
  }
  __builtin_nontemporal_store(acc, out4 + (long long)node * 4 + q);
}

extern "C" void kernel_launch(void* const* d_in, const int* in_sizes, int n_in,
                              void* d_out, int out_size, void* d_ws, size_t ws_size,
                              hipStream_t stream) {
  const int*   row    = (const int*)d_in[0];
  const int*   col    = (const int*)d_in[1];
  const float* vals   = (const float*)d_in[2];
  const float* embeds = (const float*)d_in[3];

  const int E = in_sizes[0];
  const int N = in_sizes[3] / D;

  const size_t rp_bytes = ((size_t)(N + 1) * 4 + 511) & ~(size_t)511;
  const size_t tbl_bytes = (size_t)N * D * sizeof(__half);
  const bool use_half = (ws_size >= rp_bytes + tbl_bytes) && (E >= 4);

  int*    row_ptr = (int*)d_ws;
  __half* table   = use_half ? (__half*)((char*)d_ws + rp_bytes) : nullptr;

  {
    long long chunksB = ((long long)E + 3) / 4;
    long long chunksA = use_half ? (long long)N * 2 : 0;
    long long threads = chunksB > chunksA ? chunksB : chunksA;
    int grid = (int)((threads + BLOCK - 1) / BLOCK);
    prep_kernel<<<grid, BLOCK, 0, stream>>>(row, E, embeds, N, row_ptr, table);
  }
  if (use_half) {
    int grid = (N + NPB - 1) / NPB;
    gcn_gather_kernel<<<grid, BLOCK, 0, stream>>>(
        col, vals, table, row_ptr, (f32x4*)d_out, N, E);
  } else {
    long long threads = (long long)N * 4;
    int grid = (int)((threads + BLOCK - 1) / BLOCK);
    gcn_node_f32_kernel<<<grid, BLOCK, 0, stream>>>(
        col, vals, (const f32x4*)embeds, row_ptr, (f32x4*)d_out, N, E);
  }
}